// Round 1
// baseline (194.943 us; speedup 1.0000x reference)
//
#include <hip/hip_runtime.h>
#include <math.h>

#define BATCH 8
#define DZ    32
#define NWH   48
#define NBOX  (NWH*NWH)          // 2304
#define KMAX  25
#define PIX   (384*384)          // 147456 per (k,b) slab
#define NTOT  (BATCH*NBOX)       // 18432

__device__ __forceinline__ float sigm(float x) { return 1.0f / (1.0f + expf(-x)); }
__device__ __forceinline__ float softplus(float x) {
    return fmaxf(x, 0.0f) + log1pf(expf(-fabsf(x)));
}

// ---------------- Kernel 1: conv1x1 + box decode ----------------
// writes SoA arrays to ws: x1,y1,x2,y2,prob each [B*NBOX], indexed b*NBOX+n
__global__ __launch_bounds__(256) void box_kernel(
    const float* __restrict__ z, const float* __restrict__ wz, const float* __restrict__ bz,
    const float* __restrict__ lg, const float* __restrict__ wl, const float* __restrict__ bl,
    float* __restrict__ ws)
{
    int t = blockIdx.x * 256 + threadIdx.x;
    if (t >= NTOT) return;
    int b = t / NBOX, n = t % NBOX;
    int iw = n / NWH, ih = n % NWH;

    const float* zb = z  + (((size_t)b * DZ) * NWH + iw) * NWH + ih;
    const float* lb = lg + (((size_t)b * DZ) * NWH + iw) * NWH + ih;

    float a0 = bz[0], a1 = bz[1], a2 = bz[2], a3 = bz[3], al = bl[0];
    #pragma unroll 8
    for (int d = 0; d < DZ; ++d) {
        float zv = zb[(size_t)d * NWH * NWH];
        a0 += zv * wz[d];
        a1 += zv * wz[32 + d];
        a2 += zv * wz[64 + d];
        a3 += zv * wz[96 + d];
        al += lb[(size_t)d * NWH * NWH] * wl[d];
    }
    float tx = sigm(a0), ty = sigm(a1), tw = sigm(a2), th = sigm(a3);
    float bx = 8.0f * ((float)iw + tx);           // 384*(iw+tx)/48
    float by = 8.0f * ((float)ih + ty);
    float bw = 12.0f + 36.0f * tw;                // SIZE_MIN + (MAX-MIN)*tw
    float bh = 12.0f + 36.0f * th;

    int o = b * NBOX + n;
    ws[0 * NTOT + o] = bx - 0.5f * bw;   // x1
    ws[1 * NTOT + o] = by - 0.5f * bh;   // y1
    ws[2 * NTOT + o] = bx + 0.5f * bw;   // x2
    ws[3 * NTOT + o] = by + 0.5f * bh;   // y2
    ws[4 * NTOT + o] = sigm(al);         // prob
}

// ---------------- Kernel 2: greedy NMS, one block per batch ----------------
// writes prob_few [KMAX*BATCH] at ws + 5*NTOT, layout pf[k*BATCH + b]
__global__ __launch_bounds__(256) void nms_kernel(const float* __restrict__ ws,
                                                  float* __restrict__ pf)
{
    __shared__ float x1s[NBOX], y1s[NBOX], x2s[NBOX], y2s[NBOX], pr[NBOX], mk[NBOX];
    __shared__ float redv[4];
    __shared__ int   redi[4];
    __shared__ int   selS;
    __shared__ int   idxA[KMAX];
    __shared__ int   okA[KMAX];

    int b = blockIdx.x;
    int tid = threadIdx.x;

    for (int n = tid; n < NBOX; n += 256) {
        int o = b * NBOX + n;
        x1s[n] = ws[0 * NTOT + o];
        y1s[n] = ws[1 * NTOT + o];
        x2s[n] = ws[2 * NTOT + o];
        y2s[n] = ws[3 * NTOT + o];
        float p = ws[4 * NTOT + o];
        pr[n] = p;
        mk[n] = (p > 0.1f) ? p : -INFINITY;   // masked prob; -inf == not possible
    }
    __syncthreads();

    for (int k = 0; k < KMAX; ++k) {
        // ---- block-wide argmax (first-occurrence tie-break, matches jnp.argmax) ----
        float bv = -INFINITY; int bi = 0;
        for (int n = tid; n < NBOX; n += 256) {
            float v = mk[n];
            if (v > bv) { bv = v; bi = n; }   // ascending scan keeps lowest idx on tie
        }
        #pragma unroll
        for (int off = 32; off > 0; off >>= 1) {
            float ov = __shfl_down(bv, off);
            int   oi = __shfl_down(bi, off);
            if (ov > bv || (ov == bv && oi < bi)) { bv = ov; bi = oi; }
        }
        if ((tid & 63) == 0) { redv[tid >> 6] = bv; redi[tid >> 6] = bi; }
        __syncthreads();
        if (tid == 0) {
            for (int w = 1; w < 4; ++w) {
                if (redv[w] > bv || (redv[w] == bv && redi[w] < bi)) { bv = redv[w]; bi = redi[w]; }
            }
            selS = bi;
            idxA[k] = bi;
            okA[k]  = (bv != -INFINITY) ? 1 : 0;
        }
        __syncthreads();

        int sel = selS;
        float sx1 = x1s[sel], sy1 = y1s[sel], sx2 = x2s[sel], sy2 = y2s[sel];
        float sar = (sx2 - sx1) * (sy2 - sy1);
        for (int n = tid; n < NBOX; n += 256) {
            if (mk[n] != -INFINITY) {
                float xi1 = fmaxf(sx1, x1s[n]);
                float yi1 = fmaxf(sy1, y1s[n]);
                float xi2 = fminf(sx2, x2s[n]);
                float yi2 = fminf(sy2, y2s[n]);
                float inter = fmaxf(xi2 - xi1, 0.0f) * fmaxf(yi2 - yi1, 0.0f);
                float ar    = (x2s[n] - x1s[n]) * (y2s[n] - y1s[n]);
                float uni   = sar + ar - inter;
                float iou   = inter / fmaxf(uni, 1e-8f);
                if (iou > 0.3f) mk[n] = -INFINITY;   // keep iff row <= over_t
            }
        }
        __syncthreads();
    }

    // prob_few[k] = probT[idx[k]] * maskB[idx[k]]; maskB scatter-max of ok over idx
    if (tid == 0) {
        for (int k = 0; k < KMAX; ++k) mk[idxA[k]] = 0.0f;   // reuse mk as maskB (only read at idxA)
        for (int k = 0; k < KMAX; ++k) if (okA[k]) mk[idxA[k]] = 1.0f;
        for (int k = 0; k < KMAX; ++k) pf[k * BATCH + b] = pr[idxA[k]] * mk[idxA[k]];
    }
}

// ---------------- Kernel 3: big streaming op ----------------
// out[k, b, p] = pf[k,b] * tanh(S) * softplus(wl[k,b,p]) / max(S, 1e-6),
// S = sum_k softplus(wl[k,b,p]).  One thread = 4 consecutive pixels.
__global__ __launch_bounds__(256) void big_kernel(const float* __restrict__ wlg,
                                                  const float* __restrict__ pf,
                                                  float* __restrict__ out)
{
    const size_t stride = (size_t)BATCH * PIX;     // per-k slab, elements
    size_t j = ((size_t)blockIdx.x * 256 + threadIdx.x) * 4;   // flat (b,p) index, x4
    int b = (int)(j / PIX);

    float4 sp[KMAX];
    float sx = 0.f, sy = 0.f, sz = 0.f, sw = 0.f;
    #pragma unroll
    for (int k = 0; k < KMAX; ++k) {
        float4 v = *(const float4*)(wlg + (size_t)k * stride + j);
        float4 t;
        t.x = softplus(v.x); t.y = softplus(v.y); t.z = softplus(v.z); t.w = softplus(v.w);
        sp[k] = t;
        sx += t.x; sy += t.y; sz += t.z; sw += t.w;
    }
    float4 m;
    m.x = tanhf(sx) / fmaxf(sx, 1e-6f);
    m.y = tanhf(sy) / fmaxf(sy, 1e-6f);
    m.z = tanhf(sz) / fmaxf(sz, 1e-6f);
    m.w = tanhf(sw) / fmaxf(sw, 1e-6f);
    #pragma unroll
    for (int k = 0; k < KMAX; ++k) {
        float c = pf[k * BATCH + b];
        float4 o;
        o.x = c * m.x * sp[k].x;
        o.y = c * m.y * sp[k].y;
        o.z = c * m.z * sp[k].z;
        o.w = c * m.w * sp[k].w;
        *(float4*)(out + (size_t)k * stride + j) = o;
    }
}

extern "C" void kernel_launch(void* const* d_in, const int* in_sizes, int n_in,
                              void* d_out, int out_size, void* d_ws, size_t ws_size,
                              hipStream_t stream)
{
    const float* zwhere = (const float*)d_in[0];
    const float* w_zw   = (const float*)d_in[1];
    const float* b_zw   = (const float*)d_in[2];
    const float* logit  = (const float*)d_in[3];
    const float* w_lg   = (const float*)d_in[4];
    const float* b_lg   = (const float*)d_in[5];
    const float* wlogit = (const float*)d_in[6];
    float* out = (float*)d_out;
    float* ws  = (float*)d_ws;
    float* pf  = ws + 5 * NTOT;    // prob_few [KMAX*BATCH]

    box_kernel<<<(NTOT + 255) / 256, 256, 0, stream>>>(zwhere, w_zw, b_zw, logit, w_lg, b_lg, ws);
    nms_kernel<<<BATCH, 256, 0, stream>>>(ws, pf);
    const int n4 = BATCH * PIX / 4;                 // 294912 threads
    big_kernel<<<n4 / 256, 256, 0, stream>>>(wlogit, pf, out);
}

// Round 2
// 108.885 us; speedup vs baseline: 1.7904x; 1.7904x over previous
//
#include <hip/hip_runtime.h>
#include <math.h>

#define BATCH 8
#define DZ    32
#define NWH   48
#define NBOX  (NWH*NWH)          // 2304
#define KMAX  25
#define PIX   (384*384)          // 147456 per (k,b) slab
#define NTOT  (BATCH*NBOX)       // 18432
#define SLOTS (NBOX/256)         // 9 boxes per thread in NMS

__device__ __forceinline__ float sigm(float x) { return 1.0f / (1.0f + expf(-x)); }

// fast softplus: max(x,0) + ln(1+e^{-|x|}) via hw exp2/log2. abs err ~1e-6.
__device__ __forceinline__ float sp_fast(float x) {
    return fmaxf(x, 0.0f) + __logf(1.0f + __expf(-fabsf(x)));
}

// ---------------- Kernel 1: conv1x1 + box decode (float4 over ih) ----------------
// ws planes: x1,y1,x2,y2,prob each [B*NBOX], index b*NBOX + iw*48 + ih
__global__ __launch_bounds__(256) void box_kernel(
    const float* __restrict__ z, const float* __restrict__ wz, const float* __restrict__ bz,
    const float* __restrict__ lg, const float* __restrict__ wl, const float* __restrict__ bl,
    float* __restrict__ ws)
{
    int t = blockIdx.x * 256 + threadIdx.x;       // 8*576 = 4608 threads exactly
    int b = t / 576, j = t % 576;
    int iw = j / 12, ihq = j % 12;                // 12 float4-groups of ih per row

    const float* zb = z  + (((size_t)b * DZ) * NWH + iw) * NWH + ihq * 4;
    const float* lb = lg + (((size_t)b * DZ) * NWH + iw) * NWH + ihq * 4;

    float b0 = bz[0], b1 = bz[1], b2 = bz[2], b3 = bz[3], blg = bl[0];
    float4 a0 = make_float4(b0,b0,b0,b0);
    float4 a1 = make_float4(b1,b1,b1,b1);
    float4 a2 = make_float4(b2,b2,b2,b2);
    float4 a3 = make_float4(b3,b3,b3,b3);
    float4 al = make_float4(blg,blg,blg,blg);

    #pragma unroll 8
    for (int d = 0; d < DZ; ++d) {
        float4 zv = *(const float4*)(zb + (size_t)d * NBOX);
        float4 lv = *(const float4*)(lb + (size_t)d * NBOX);
        float w0 = wz[d], w1 = wz[32+d], w2 = wz[64+d], w3 = wz[96+d], wv = wl[d];
        a0.x += zv.x*w0; a0.y += zv.y*w0; a0.z += zv.z*w0; a0.w += zv.w*w0;
        a1.x += zv.x*w1; a1.y += zv.y*w1; a1.z += zv.z*w1; a1.w += zv.w*w1;
        a2.x += zv.x*w2; a2.y += zv.y*w2; a2.z += zv.z*w2; a2.w += zv.w*w2;
        a3.x += zv.x*w3; a3.y += zv.y*w3; a3.z += zv.z*w3; a3.w += zv.w*w3;
        al.x += lv.x*wv; al.y += lv.y*wv; al.z += lv.z*wv; al.w += lv.w*wv;
    }

    float4 X1, Y1, X2, Y2, P;
    float txv[4] = {a0.x,a0.y,a0.z,a0.w};
    float tyv[4] = {a1.x,a1.y,a1.z,a1.w};
    float twv[4] = {a2.x,a2.y,a2.z,a2.w};
    float thv[4] = {a3.x,a3.y,a3.z,a3.w};
    float alv[4] = {al.x,al.y,al.z,al.w};
    float x1o[4], y1o[4], x2o[4], y2o[4], po[4];
    #pragma unroll
    for (int c = 0; c < 4; ++c) {
        float tx = sigm(txv[c]), ty = sigm(tyv[c]), tw = sigm(twv[c]), th = sigm(thv[c]);
        float bx = 8.0f * ((float)iw + tx);
        float by = 8.0f * ((float)(ihq*4 + c) + ty);
        float bw = 12.0f + 36.0f * tw;
        float bh = 12.0f + 36.0f * th;
        x1o[c] = bx - 0.5f*bw;  y1o[c] = by - 0.5f*bh;
        x2o[c] = bx + 0.5f*bw;  y2o[c] = by + 0.5f*bh;
        po[c]  = sigm(alv[c]);
    }
    X1 = make_float4(x1o[0],x1o[1],x1o[2],x1o[3]);
    Y1 = make_float4(y1o[0],y1o[1],y1o[2],y1o[3]);
    X2 = make_float4(x2o[0],x2o[1],x2o[2],x2o[3]);
    Y2 = make_float4(y2o[0],y2o[1],y2o[2],y2o[3]);
    P  = make_float4(po[0], po[1], po[2], po[3]);

    int o = b * NBOX + iw * NWH + ihq * 4;
    *(float4*)(ws + 0*NTOT + o) = X1;
    *(float4*)(ws + 1*NTOT + o) = Y1;
    *(float4*)(ws + 2*NTOT + o) = X2;
    *(float4*)(ws + 3*NTOT + o) = Y2;
    *(float4*)(ws + 4*NTOT + o) = P;
}

// ---------------- Kernel 2: greedy NMS, one block per batch, boxes in registers ----------------
__global__ __launch_bounds__(256) void nms_kernel(const float* __restrict__ ws,
                                                  float* __restrict__ pf)
{
    __shared__ float4 boxS[NBOX];     // for selected-box broadcast + final gather
    __shared__ float  prS[NBOX];
    __shared__ float  redv[4];
    __shared__ int    redi[4];
    __shared__ float4 selB;
    __shared__ int    idxA[KMAX];
    __shared__ int    okA[KMAX];

    int b = blockIdx.x, tid = threadIdx.x;

    float x1r[SLOTS], y1r[SLOTS], x2r[SLOTS], y2r[SLOTS], arr[SLOTS], mkv[SLOTS];
    #pragma unroll
    for (int s = 0; s < SLOTS; ++s) {
        int n = tid + 256*s;
        int o = b * NBOX + n;
        float x1 = ws[0*NTOT+o], y1 = ws[1*NTOT+o], x2 = ws[2*NTOT+o], y2 = ws[3*NTOT+o];
        float p  = ws[4*NTOT+o];
        x1r[s]=x1; y1r[s]=y1; x2r[s]=x2; y2r[s]=y2;
        arr[s] = (x2-x1)*(y2-y1);
        mkv[s] = (p > 0.1f) ? p : -INFINITY;
        boxS[n] = make_float4(x1,y1,x2,y2);
        prS[n]  = p;
    }
    __syncthreads();

    for (int k = 0; k < KMAX; ++k) {
        float4 sb = make_float4(0,0,0,0); float sar = 0.f;
        if (k > 0) { sb = selB; sar = (sb.z - sb.x) * (sb.w - sb.y); }

        float bv = -INFINITY; int bi = 0;
        #pragma unroll
        for (int s = 0; s < SLOTS; ++s) {
            if (k > 0 && mkv[s] != -INFINITY) {
                float xi1 = fmaxf(sb.x, x1r[s]);
                float yi1 = fmaxf(sb.y, y1r[s]);
                float xi2 = fminf(sb.z, x2r[s]);
                float yi2 = fminf(sb.w, y2r[s]);
                float inter = fmaxf(xi2 - xi1, 0.f) * fmaxf(yi2 - yi1, 0.f);
                float uni   = sar + arr[s] - inter;
                float iou   = inter / fmaxf(uni, 1e-8f);
                if (iou > 0.3f) mkv[s] = -INFINITY;
            }
            float v = mkv[s];
            if (v > bv) { bv = v; bi = tid + 256*s; }   // ascending n keeps lowest on tie
        }
        #pragma unroll
        for (int off = 32; off > 0; off >>= 1) {
            float ov = __shfl_down(bv, off);
            int   oi = __shfl_down(bi, off);
            if (ov > bv || (ov == bv && oi < bi)) { bv = ov; bi = oi; }
        }
        if ((tid & 63) == 0) { redv[tid >> 6] = bv; redi[tid >> 6] = bi; }
        __syncthreads();
        if (tid == 0) {
            for (int w = 1; w < 4; ++w)
                if (redv[w] > bv || (redv[w] == bv && redi[w] < bi)) { bv = redv[w]; bi = redi[w]; }
            idxA[k] = bi;
            okA[k]  = (bv != -INFINITY) ? 1 : 0;
            selB    = boxS[bi];
        }
        __syncthreads();
    }

    if (tid == 0) {
        // maskB gathered at idxA[k] = max over k2 with same idx of ok[k2]
        #pragma unroll 1
        for (int k = 0; k < KMAX; ++k) {
            float m = 0.f;
            for (int k2 = 0; k2 < KMAX; ++k2)
                if (idxA[k2] == idxA[k] && okA[k2]) m = 1.f;
            pf[k * BATCH + b] = prS[idxA[k]] * m;
        }
    }
}

// ---------------- Kernel 3: big streaming op (fast transcendentals) ----------------
__global__ __launch_bounds__(256) void big_kernel(const float* __restrict__ wlg,
                                                  const float* __restrict__ pf,
                                                  float* __restrict__ out)
{
    const size_t stride = (size_t)BATCH * PIX;
    size_t j = ((size_t)blockIdx.x * 256 + threadIdx.x) * 4;
    int b = (int)(j / PIX);

    float4 sp[KMAX];
    float sx = 0.f, sy = 0.f, sz = 0.f, sw = 0.f;
    #pragma unroll
    for (int k = 0; k < KMAX; ++k) {
        float4 v = *(const float4*)(wlg + (size_t)k * stride + j);
        float4 t;
        t.x = sp_fast(v.x); t.y = sp_fast(v.y); t.z = sp_fast(v.z); t.w = sp_fast(v.w);
        sp[k] = t;
        sx += t.x; sy += t.y; sz += t.z; sw += t.w;
    }
    // m = tanh(S)/max(S,1e-6), S >= 0:  tanh(S) = (1-e^{-2S})/(1+e^{-2S})
    float4 m;
    {
        float tx = __expf(-2.f*sx), ty = __expf(-2.f*sy), tz = __expf(-2.f*sz), tw = __expf(-2.f*sw);
        m.x = (1.f - tx) * __builtin_amdgcn_rcpf(1.f + tx) * __builtin_amdgcn_rcpf(fmaxf(sx, 1e-6f));
        m.y = (1.f - ty) * __builtin_amdgcn_rcpf(1.f + ty) * __builtin_amdgcn_rcpf(fmaxf(sy, 1e-6f));
        m.z = (1.f - tz) * __builtin_amdgcn_rcpf(1.f + tz) * __builtin_amdgcn_rcpf(fmaxf(sz, 1e-6f));
        m.w = (1.f - tw) * __builtin_amdgcn_rcpf(1.f + tw) * __builtin_amdgcn_rcpf(fmaxf(sw, 1e-6f));
    }
    #pragma unroll
    for (int k = 0; k < KMAX; ++k) {
        float c = pf[k * BATCH + b];
        float4 o;
        o.x = c * m.x * sp[k].x;
        o.y = c * m.y * sp[k].y;
        o.z = c * m.z * sp[k].z;
        o.w = c * m.w * sp[k].w;
        *(float4*)(out + (size_t)k * stride + j) = o;
    }
}

extern "C" void kernel_launch(void* const* d_in, const int* in_sizes, int n_in,
                              void* d_out, int out_size, void* d_ws, size_t ws_size,
                              hipStream_t stream)
{
    const float* zwhere = (const float*)d_in[0];
    const float* w_zw   = (const float*)d_in[1];
    const float* b_zw   = (const float*)d_in[2];
    const float* logit  = (const float*)d_in[3];
    const float* w_lg   = (const float*)d_in[4];
    const float* b_lg   = (const float*)d_in[5];
    const float* wlogit = (const float*)d_in[6];
    float* out = (float*)d_out;
    float* ws  = (float*)d_ws;
    float* pf  = ws + 5 * NTOT;    // prob_few [KMAX*BATCH]

    box_kernel<<<(BATCH*576)/256, 256, 0, stream>>>(zwhere, w_zw, b_zw, logit, w_lg, b_lg, ws);
    nms_kernel<<<BATCH, 256, 0, stream>>>(ws, pf);
    const int n4 = BATCH * PIX / 4;
    big_kernel<<<n4 / 256, 256, 0, stream>>>(wlogit, pf, out);
}